// Round 15
// baseline (9399.261 us; speedup 1.0000x reference)
//
#include <hip/hip_runtime.h>
#include <math.h>

// ---------------------------------------------------------------------------
// Seq2SeqLSTM on MI355X -- Round 14: 2 rows per chain WG (halve L2 demand)
// + fT hop removed (all-P redundant argmax reduce).
//
// R12/R13 invariant: megadec chain step 17.6us under BOTH role layouts vs
// k_pipe's 10.9 -> per-XCD L2 read BW (~1.8TB/s) is the binder at 32 chain
// WGs/XCD (2.9TB/s demanded). Fix: each chain WG computes 2 rows sharing one
// weight stream -> 32 WGs/role, 16/XCD, 1.5TB/s < ceiling. part[8][4096]
// (128KB LDS, union w/ P buffers = 138KB). Gate arithmetic order unchanged
// -> absmax must stay bit-identical. Boundary: drop P0-reduce+fT hop; every
// P WG reduces all 64 slices + gathers emb itself; B2 h1R backpressure = fP.
// ---------------------------------------------------------------------------

#define B     64
#define SLEN  64
#define TLEN  32
#define HID   256
#define EMBD  256
#define G4    1024
#define VOC   32000
#define NPRED 31
#define FBASE 64

typedef unsigned long long u64;

__device__ __forceinline__ float sigf(float x){ return 1.0f/(1.0f+__expf(-x)); }

__device__ __forceinline__ void gstoref(float* p, float v){
  __hip_atomic_store(p, v, __ATOMIC_RELAXED, __HIP_MEMORY_SCOPE_AGENT);
}
__device__ __forceinline__ void gstorei(int* p, int v){
  __hip_atomic_store(p, v, __ATOMIC_RELAXED, __HIP_MEMORY_SCOPE_AGENT);
}
__device__ __forceinline__ float gloadf(const float* p){
  return __hip_atomic_load(p, __ATOMIC_RELAXED, __HIP_MEMORY_SCOPE_AGENT);
}
__device__ __forceinline__ int gload32(const int* p){
  return __hip_atomic_load(p, __ATOMIC_RELAXED, __HIP_MEMORY_SCOPE_AGENT);
}

// --------------------------------- zero ------------------------------------
__global__ void k_zero(int* __restrict__ p){
  p[threadIdx.x] = 0;    // block 512
}

// ------------------------------- transpose ----------------------------------
__global__ __launch_bounds__(256) void k_tr(const float* __restrict__ src,
                                            float* __restrict__ dst){
  __shared__ float t[64][65];
  const int r0 = blockIdx.x*64, c0 = blockIdx.y*64;
  const int lr = threadIdx.x>>6, lc = threadIdx.x&63;
  #pragma unroll
  for (int i=0;i<16;i++){
    int r = lr + i*4;
    t[r][lc] = src[(size_t)(r0+r)*256 + c0+lc];
  }
  __syncthreads();
  #pragma unroll
  for (int i=0;i<16;i++){
    int c = lr + i*4;
    dst[(size_t)(c0+c)*1024 + r0+lc] = t[lc][c];
  }
}

// --------------------------------- xproj -----------------------------------
// layout: out[(pos*64 + r)*G4 + j]
__global__ __launch_bounds__(256) void k_xproj(
    const int* __restrict__ tok, int tok_stride, int pos0,
    const float* __restrict__ emb, const float* __restrict__ W,
    const float* __restrict__ b0, float* __restrict__ out)
{
  __shared__ float xT[128][64];
  const int tid  = threadIdx.x;
  const int lane = tid & 63;
  const int wv   = __builtin_amdgcn_readfirstlane(tid >> 6);
  const int pos  = pos0 + blockIdx.y;
  const int jbase= blockIdx.x*32 + wv*8;

  const int rS = tid >> 2, klane = tid & 3;
  const int tokrow = tok[rS*tok_stride + pos];
  const float* xsrc = emb + (size_t)tokrow*EMBD;

  float acc[8];
  #pragma unroll
  for (int jj=0;jj<8;jj++) acc[jj]=0.f;

  for (int c=0;c<2;c++){
    __syncthreads();
    #pragma unroll
    for (int i=0;i<32;i++){
      int k = klane + 4*i;
      xT[k][rS] = xsrc[c*128 + k];
    }
    __syncthreads();
    for (int kc=0;kc<8;kc++){
      float x[16];
      #pragma unroll
      for (int i=0;i<16;i++) x[i] = xT[kc*16+i][lane];
      #pragma unroll
      for (int jj=0;jj<8;jj++){
        const float* Wp = W + (size_t)(jbase+jj)*EMBD + c*128 + kc*16;
        float s = 0.f;
        #pragma unroll
        for (int i=0;i<16;i++) s += Wp[i]*x[i];
        acc[jj] += s;
      }
    }
  }
  #pragma unroll
  for (int jj=0;jj<8;jj++){
    int j = jbase+jj;
    out[((size_t)pos*64 + lane)*G4 + j] = acc[jj] + b0[j];
  }
}

// ------------------------------- dotpart ------------------------------------
__device__ __forceinline__ float4 dotpart(const float4* __restrict__ Wq,
                                          const float* __restrict__ hs,
                                          int kq, int jg){
  float ax=0.f, ay=0.f, az=0.f, aw=0.f;
  const float4* __restrict__ hq = (const float4*)(hs + (kq<<6));
  const float4* __restrict__ w  = Wq + (size_t)(kq<<6)*256 + jg;
  #pragma unroll 4
  for (int kk=0; kk<16; ++kk){
    float4 h4 = hq[kk];
    float4 w0 = w[0];
    float4 w1 = w[256];
    float4 w2 = w[512];
    float4 w3 = w[768];
    ax += w0.x*h4.x; ay += w0.y*h4.x; az += w0.z*h4.x; aw += w0.w*h4.x;
    ax += w1.x*h4.y; ay += w1.y*h4.y; az += w1.z*h4.y; aw += w1.w*h4.y;
    ax += w2.x*h4.z; ay += w2.y*h4.z; az += w2.z*h4.z; aw += w2.w*h4.z;
    ax += w3.x*h4.w; ay += w3.y*h4.w; az += w3.z*h4.w; aw += w3.w*h4.w;
    w += 1024;
  }
  return make_float4(ax,ay,az,aw);
}

// 2-row variant: same weight stream, two h vectors. Per-row accumulation
// order identical to dotpart -> bitwise-identical gate values.
__device__ __forceinline__ void dotpart2(const float4* __restrict__ Wq,
    const float* __restrict__ ha, const float* __restrict__ hb,
    int kq, int jg, float4& A, float4& Bv){
  float ax=0.f,ay=0.f,az=0.f,aw=0.f, bx=0.f,by=0.f,bz=0.f,bw=0.f;
  const float4* __restrict__ hqa = (const float4*)(ha + (kq<<6));
  const float4* __restrict__ hqb = (const float4*)(hb + (kq<<6));
  const float4* __restrict__ w   = Wq + (size_t)(kq<<6)*256 + jg;
  #pragma unroll 2
  for (int kk=0; kk<16; ++kk){
    float4 h4a = hqa[kk], h4b = hqb[kk];
    float4 w0 = w[0];
    float4 w1 = w[256];
    float4 w2 = w[512];
    float4 w3 = w[768];
    ax += w0.x*h4a.x; ay += w0.y*h4a.x; az += w0.z*h4a.x; aw += w0.w*h4a.x;
    ax += w1.x*h4a.y; ay += w1.y*h4a.y; az += w1.z*h4a.y; aw += w1.w*h4a.y;
    ax += w2.x*h4a.z; ay += w2.y*h4a.z; az += w2.z*h4a.z; aw += w2.w*h4a.z;
    ax += w3.x*h4a.w; ay += w3.y*h4a.w; az += w3.z*h4a.w; aw += w3.w*h4a.w;
    bx += w0.x*h4b.x; by += w0.y*h4b.x; bz += w0.z*h4b.x; bw += w0.w*h4b.x;
    bx += w1.x*h4b.y; by += w1.y*h4b.y; bz += w1.z*h4b.y; bw += w1.w*h4b.y;
    bx += w2.x*h4b.z; by += w2.y*h4b.z; bz += w2.z*h4b.z; bw += w2.w*h4b.z;
    bx += w3.x*h4b.w; by += w3.y*h4b.w; bz += w3.z*h4b.w; bw += w3.w*h4b.w;
    w += 1024;
  }
  A  = make_float4(ax,ay,az,aw);
  Bv = make_float4(bx,by,bz,bw);
}

// --------------------------- encoder pipe (R8) -------------------------------
__global__ __launch_bounds__(1024) void k_pipe(
    const float* __restrict__ xp, int nsteps,
    const float* __restrict__ WT0, const float* __restrict__ WT1i,
    const float* __restrict__ WT1h, const float* __restrict__ b1,
    float* __restrict__ h0P, float* __restrict__ h1P,
    float* __restrict__ c0P, float* __restrict__ c1P,
    float* __restrict__ h0R, float* __restrict__ p1R,
    int* __restrict__ fA, int* __restrict__ fB1, int* __restrict__ fB2,
    int fbase, int initzero)
{
  __shared__ __align__(16) float part[4][4096];
  __shared__ float xps[1024];
  __shared__ __align__(16) float hloc[256];
  __shared__ float padL[4096];
  const int tid  = threadIdx.x;
  const int kq   = tid >> 8, jg = tid & 255;
  const int role = blockIdx.x >> 6;
  const int r    = blockIdx.x & 63;
  if (nsteps < 0){ padL[tid] = xp[tid]; h0R[tid] = padL[tid ^ 1]; }

  if (role == 0){
    float c0 = 0.f;
    if (tid < HID){
      if (initzero){ c0 = 0.f; hloc[tid] = 0.f; }
      else { c0 = c0P[tid*64 + r]; hloc[tid] = h0P[tid*64 + r]; }
    }
    __syncthreads();
    const float4* W4 = (const float4*)WT0;
    for (int q = 0; q < nsteps; ++q){
      float xv = xp[((size_t)q*64 + r)*G4 + tid];
      if (tid == 0 && q >= 4){
        int tgt = fbase + q - 3, g = 0;
        while (gload32(fB1 + r) < tgt && ++g < (1<<24)) {}
      }
      float4 a = dotpart(W4, hloc, kq, jg);
      xps[tid] = xv;
      *(float4*)&part[kq][jg<<2] = a;
      __syncthreads();
      if (tid < HID){
        float g0 = part[0][tid]+part[1][tid]+part[2][tid]+part[3][tid] + xps[tid];
        float g1 = part[0][HID+tid]+part[1][HID+tid]+part[2][HID+tid]+part[3][HID+tid] + xps[HID+tid];
        float g2 = part[0][2*HID+tid]+part[1][2*HID+tid]+part[2][2*HID+tid]+part[3][2*HID+tid] + xps[2*HID+tid];
        float g3 = part[0][3*HID+tid]+part[1][3*HID+tid]+part[2][3*HID+tid]+part[3][3*HID+tid] + xps[3*HID+tid];
        c0 = sigf(g1)*c0 + sigf(g0)*tanhf(g2);
        float h = sigf(g3)*tanhf(c0);
        hloc[tid] = h;
        gstoref(h0R + (q&3)*16384 + r*256 + tid, h);
        asm volatile("s_waitcnt vmcnt(0)" ::: "memory");
      }
      __syncthreads();
      if (tid == 0) gstorei(fA + r, fbase + q + 1);
    }
    if (tid < HID){ c0P[tid*64 + r] = c0; h0P[tid*64 + r] = hloc[tid]; }
  }
  else if (role == 1){
    const float4* W4 = (const float4*)WT1i;
    for (int q = 0; q < nsteps; ++q){
      if (tid == 0){
        int tgt = fbase + q + 1, g = 0;
        while (gload32(fA + r) < tgt && ++g < (1<<24)) {}
        if (q >= 4){
          int t2 = fbase + q - 3; g = 0;
          while (gload32(fB2 + r) < t2 && ++g < (1<<24)) {}
        }
      }
      __syncthreads();
      if (tid < HID) hloc[tid] = gloadf(h0R + (q&3)*16384 + r*256 + tid);
      __syncthreads();
      float4 a = dotpart(W4, hloc, kq, jg);
      *(float4*)&part[kq][jg<<2] = a;
      __syncthreads();
      float p = part[0][tid]+part[1][tid]+part[2][tid]+part[3][tid];
      gstoref(p1R + (q&3)*65536 + r*1024 + tid, p);
      asm volatile("s_waitcnt vmcnt(0)" ::: "memory");
      __syncthreads();
      if (tid == 0) gstorei(fB1 + r, fbase + q + 1);
    }
  }
  else {
    float c1 = 0.f, bb0=0.f, bb1=0.f, bb2=0.f, bb3=0.f;
    if (tid < HID){
      bb0 = b1[tid]; bb1 = b1[HID+tid]; bb2 = b1[2*HID+tid]; bb3 = b1[3*HID+tid];
      if (initzero){ c1 = 0.f; hloc[tid] = 0.f; }
      else { c1 = c1P[tid*64 + r]; hloc[tid] = h1P[tid*64 + r]; }
    }
    __syncthreads();
    const float4* W4 = (const float4*)WT1h;
    for (int q = 0; q < nsteps; ++q){
      if (tid == 0){
        int tgt = fbase + q + 1, g = 0;
        while (gload32(fB1 + r) < tgt && ++g < (1<<24)) {}
      }
      __syncthreads();
      xps[tid] = gloadf(p1R + (q&3)*65536 + r*1024 + tid);
      asm volatile("s_waitcnt vmcnt(0)" ::: "memory");
      __syncthreads();
      if (tid == 0) gstorei(fB2 + r, fbase + q + 1);
      float4 a = dotpart(W4, hloc, kq, jg);
      *(float4*)&part[kq][jg<<2] = a;
      __syncthreads();
      if (tid < HID){
        float g0 = part[0][tid]+part[1][tid]+part[2][tid]+part[3][tid] + xps[tid] + bb0;
        float g1 = part[0][HID+tid]+part[1][HID+tid]+part[2][HID+tid]+part[3][HID+tid] + xps[HID+tid] + bb1;
        float g2 = part[0][2*HID+tid]+part[1][2*HID+tid]+part[2][2*HID+tid]+part[3][2*HID+tid] + xps[2*HID+tid] + bb2;
        float g3 = part[0][3*HID+tid]+part[1][3*HID+tid]+part[2][3*HID+tid]+part[3][3*HID+tid] + xps[3*HID+tid] + bb3;
        c1 = sigf(g1)*c1 + sigf(g0)*tanhf(g2);
        float h = sigf(g3)*tanhf(c1);
        hloc[tid] = h;
        if (q == nsteps-1) h1P[tid*64 + r] = h;
      }
      __syncthreads();
    }
    if (tid < HID) c1P[tid*64 + r] = c1;
  }
}

// ------------------------- persistent decoder --------------------------------
// flags: fA[0..31] fB1[64..95] fB2[128..159] (per chain WG, FBASE-cumulative)
//        fH[192..255] fP[256..319] fX[320..383] (per row / per P slice)
// WG map: xcd=bid&7, slot=bid>>3. xcd<6: slot<16 -> role=xcd>>1,
//         w=((xcd&1)<<4)|slot (rows 2w,2w+1); slot>=16 -> exit.
//         xcd>=6: role P, v=((xcd&1)<<5)|slot.
__global__ __launch_bounds__(1024) void k_megadec(
    float* xp,
    const float* __restrict__ WT0, const float* __restrict__ WT1i,
    const float* __restrict__ WT1h, const float* __restrict__ b1,
    const float* __restrict__ Wih0, const float* __restrict__ b0,
    const float* __restrict__ emb,
    const float* __restrict__ Wout, const float* __restrict__ bout,
    float* __restrict__ dout,
    const float* __restrict__ h0P, const float* __restrict__ h1P,
    const float* __restrict__ c0P, const float* __restrict__ c1P,
    float* __restrict__ h0R, float* __restrict__ p1R, float* __restrict__ h1R,
    float* __restrict__ pPv, int* __restrict__ pPi,
    int* __restrict__ flags)
{
  __shared__ union {
    struct {
      float part[8][4096];   // 128 KB  [kq*2+row][j]
      float xps[2][1024];    //   8 KB
      float hloc[2][256];    //   2 KB
    } c;
    struct {
      float htp[256*65];     //  65 KB
      float red[1024];       //   4 KB
      int   idx[1024];       //   4 KB
      int   tok[64];
    } p;
  } S;

  int* fA = flags;        int* fB1 = flags + 64;  int* fB2 = flags + 128;
  int* fH = flags + 192;  int* fP  = flags + 256; int* fX  = flags + 320;

  const int tid  = threadIdx.x;
  const int lane = tid & 63;
  const int wv   = __builtin_amdgcn_readfirstlane(tid >> 6);
  const int kq   = tid >> 8, jg = tid & 255;
  const int xcd  = blockIdx.x & 7;
  const int slot = blockIdx.x >> 3;
  if (xcd < 6 && slot >= 16) return;
  const int role = (xcd < 6) ? (xcd >> 1) : 3;
  const int w    = ((xcd & 1) << 4) | slot;      // chain WG id 0..31
  const int v    = ((xcd & 1) << 5) | slot;      // pred slice 0..63

  // =========================== role A: layer 0 =============================
  if (role == 0){
    const int r0 = 2*w, r1 = 2*w+1;
    const int u = tid >> 1, row = tid & 1, rr = 2*w + row;
    float c0 = 0.f;
    if (tid < 512){ c0 = c0P[u*64 + rr]; S.c.hloc[row][u] = h0P[u*64 + rr]; }
    __syncthreads();
    const float4* W4 = (const float4*)WT0;
    int cum = 0;
    for (int t = 0; t < NPRED; ++t)
    for (int p = 0; p <= t; ++p, ++cum){
      if (wv == 0){
        if (lane == 0 && cum >= 4){
          int tgt = FBASE + cum - 3, g = 0;
          while (gload32(fB1 + w) < tgt && ++g < (1<<24)) {}
        }
        if (p == t && t >= 1){
          int g = 0;
          while (!__all(gload32(fX + lane) >= t) && ++g < (1<<24)) {}
        }
      }
      __syncthreads();
      const float* xa0 = xp + ((size_t)p*64 + r0)*G4 + tid;
      const float* xa1 = xp + ((size_t)p*64 + r1)*G4 + tid;
      float xv0 = (p == t) ? gloadf(xa0) : *xa0;
      float xv1 = (p == t) ? gloadf(xa1) : *xa1;
      float4 a, bv;
      dotpart2(W4, S.c.hloc[0], S.c.hloc[1], kq, jg, a, bv);
      S.c.xps[0][tid] = xv0; S.c.xps[1][tid] = xv1;
      *(float4*)&S.c.part[kq*2+0][jg<<2] = a;
      *(float4*)&S.c.part[kq*2+1][jg<<2] = bv;
      __syncthreads();
      if (tid < 512){
        float g0 = S.c.part[row][u]      +S.c.part[2+row][u]      +S.c.part[4+row][u]      +S.c.part[6+row][u]      + S.c.xps[row][u];
        float g1 = S.c.part[row][HID+u]  +S.c.part[2+row][HID+u]  +S.c.part[4+row][HID+u]  +S.c.part[6+row][HID+u]  + S.c.xps[row][HID+u];
        float g2 = S.c.part[row][2*HID+u]+S.c.part[2+row][2*HID+u]+S.c.part[4+row][2*HID+u]+S.c.part[6+row][2*HID+u]+ S.c.xps[row][2*HID+u];
        float g3 = S.c.part[row][3*HID+u]+S.c.part[2+row][3*HID+u]+S.c.part[4+row][3*HID+u]+S.c.part[6+row][3*HID+u]+ S.c.xps[row][3*HID+u];
        c0 = sigf(g1)*c0 + sigf(g0)*tanhf(g2);
        float h = sigf(g3)*tanhf(c0);
        S.c.hloc[row][u] = h;
        gstoref(h0R + (cum&3)*16384 + rr*256 + u, h);
        asm volatile("s_waitcnt vmcnt(0)" ::: "memory");
      }
      __syncthreads();
      if (tid == 0) gstorei(fA + w, FBASE + cum + 1);
    }
  }
  // =========================== role B1: Wih1.h0 ============================
  else if (role == 1){
    const int u = tid >> 1, row = tid & 1, rr = 2*w + row;
    const float4* W4 = (const float4*)WT1i;
    int cum = 0;
    for (int t = 0; t < NPRED; ++t)
    for (int p = 0; p <= t; ++p, ++cum){
      if (tid == 0){
        int tgt = FBASE + cum + 1, g = 0;
        while (gload32(fA + w) < tgt && ++g < (1<<24)) {}
        if (cum >= 4){
          int t2 = FBASE + cum - 3; g = 0;
          while (gload32(fB2 + w) < t2 && ++g < (1<<24)) {}
        }
      }
      __syncthreads();
      if (tid < 512) S.c.hloc[row][u] = gloadf(h0R + (cum&3)*16384 + rr*256 + u);
      __syncthreads();
      float4 a, bv;
      dotpart2(W4, S.c.hloc[0], S.c.hloc[1], kq, jg, a, bv);
      *(float4*)&S.c.part[kq*2+0][jg<<2] = a;
      *(float4*)&S.c.part[kq*2+1][jg<<2] = bv;
      __syncthreads();
      float pp0 = S.c.part[0][tid]+S.c.part[2][tid]+S.c.part[4][tid]+S.c.part[6][tid];
      float pp1 = S.c.part[1][tid]+S.c.part[3][tid]+S.c.part[5][tid]+S.c.part[7][tid];
      gstoref(p1R + (cum&3)*65536 + (size_t)(2*w)*1024   + tid, pp0);
      gstoref(p1R + (cum&3)*65536 + (size_t)(2*w+1)*1024 + tid, pp1);
      asm volatile("s_waitcnt vmcnt(0)" ::: "memory");
      __syncthreads();
      if (tid == 0) gstorei(fB1 + w, FBASE + cum + 1);
    }
  }
  // ================== role B2: Whh1.h1 + combine + act =====================
  else if (role == 2){
    const int u = tid >> 1, row = tid & 1, rr = 2*w + row;
    float c1 = 0.f, bb0=0.f, bb1=0.f, bb2=0.f, bb3=0.f;
    if (tid < 512){
      bb0 = b1[u]; bb1 = b1[HID+u]; bb2 = b1[2*HID+u]; bb3 = b1[3*HID+u];
      c1 = c1P[u*64 + rr]; S.c.hloc[row][u] = h1P[u*64 + rr];
    }
    __syncthreads();
    const float4* W4 = (const float4*)WT1h;
    int cum = 0;
    for (int t = 0; t < NPRED; ++t)
    for (int p = 0; p <= t; ++p, ++cum){
      if (tid == 0){
        int tgt = FBASE + cum + 1, g = 0;
        while (gload32(fB1 + w) < tgt && ++g < (1<<24)) {}
      }
      __syncthreads();
      S.c.xps[0][tid] = gloadf(p1R + (cum&3)*65536 + (size_t)(2*w)*1024   + tid);
      S.c.xps[1][tid] = gloadf(p1R + (cum&3)*65536 + (size_t)(2*w+1)*1024 + tid);
      asm volatile("s_waitcnt vmcnt(0)" ::: "memory");
      __syncthreads();
      if (tid == 0) gstorei(fB2 + w, FBASE + cum + 1);
      float4 a, bv;
      dotpart2(W4, S.c.hloc[0], S.c.hloc[1], kq, jg, a, bv);
      *(float4*)&S.c.part[kq*2+0][jg<<2] = a;
      *(float4*)&S.c.part[kq*2+1][jg<<2] = bv;
      __syncthreads();
      if (tid < 512){
        float g0 = S.c.part[row][u]      +S.c.part[2+row][u]      +S.c.part[4+row][u]      +S.c.part[6+row][u]      + S.c.xps[row][u]       + bb0;
        float g1 = S.c.part[row][HID+u]  +S.c.part[2+row][HID+u]  +S.c.part[4+row][HID+u]  +S.c.part[6+row][HID+u]  + S.c.xps[row][HID+u]   + bb1;
        float g2 = S.c.part[row][2*HID+u]+S.c.part[2+row][2*HID+u]+S.c.part[4+row][2*HID+u]+S.c.part[6+row][2*HID+u]+ S.c.xps[row][2*HID+u] + bb2;
        float g3 = S.c.part[row][3*HID+u]+S.c.part[2+row][3*HID+u]+S.c.part[4+row][3*HID+u]+S.c.part[6+row][3*HID+u]+ S.c.xps[row][3*HID+u] + bb3;
        c1 = sigf(g1)*c1 + sigf(g0)*tanhf(g2);
        float h = sigf(g3)*tanhf(c1);
        S.c.hloc[row][u] = h;
      }
      __syncthreads();
      if (p == t){
        if (wv == 0 && t >= 2){         // h1R slot reuse gated by pred(t-2)
          int g = 0;
          while (!__all(gload32(fP + lane) >= t-1) && ++g < (1<<24)) {}
        }
        __syncthreads();
        if (tid < 512){
          gstoref(h1R + (t&1)*16384 + rr*256 + u, S.c.hloc[row][u]);
          asm volatile("s_waitcnt vmcnt(0)" ::: "memory");
        }
        __syncthreads();
        if (tid == 0){
          gstorei(fH + 2*w,   t + 1);
          gstorei(fH + 2*w+1, t + 1);
        }
      }
    }
  }
  // ================== role P: pred + argmax + xproj ========================
  else {
    const int v0 = v * 500;
    const int rr = tid >> 4;          // row for xproj
    const int jl = tid & 15;          // j within slice
    const float b0v = b0[v*16 + jl];

    for (int t = 0; t < NPRED; ++t){
      if (wv == 0){
        int g = 0;
        while (!__all(gload32(fH + lane) >= t+1) && ++g < (1<<24))
          __builtin_amdgcn_s_sleep(4);
      }
      __syncthreads();
      // stage h1R[t&1] ([r][k]) -> htp[k*65+r]
      {
        const float* src = h1R + (size_t)(t&1)*16384;
        #pragma unroll
        for (int i=0;i<16;i++){
          int idx = tid + i*1024;
          float vl = gloadf(src + idx);
          S.p.htp[(idx & 255)*65 + (idx >> 8)] = vl;
        }
      }
      __syncthreads();
      // pred: wave wv, lane=row; vv = v0 + wv + 16*i (guard <500)
      float best = -INFINITY; int bi = 0x7fffffff;
      for (int ib = 0; ib < 4; ++ib){
        float acc[8];
        #pragma unroll
        for (int jj=0;jj<8;jj++){
          int i = ib*8+jj;
          acc[jj] = (wv + 16*i < 500) ? bout[v0 + wv + 16*i] : 0.f;
        }
        for (int kc = 0; kc < 16; ++kc){
          float x[16];
          #pragma unroll
          for (int u2=0;u2<16;u2++) x[u2] = S.p.htp[(kc*16+u2)*65 + lane];
          #pragma unroll
          for (int jj=0;jj<8;jj++){
            int i = ib*8+jj;
            if (wv + 16*i < 500){
              const float* Wp = Wout + (size_t)(v0 + wv + 16*i)*HID + kc*16;
              #pragma unroll
              for (int u2=0;u2<16;u2++) acc[jj] += Wp[u2]*x[u2];
            }
          }
        }
        #pragma unroll
        for (int jj=0;jj<8;jj++){
          int i = ib*8+jj;
          if (wv + 16*i < 500){
            int vv = v0 + wv + 16*i;
            dout[((size_t)lane*NPRED + t)*VOC + vv] = acc[jj];
            if (acc[jj] > best){ best = acc[jj]; bi = vv; }
          }
        }
      }
      S.p.red[wv*64 + lane] = best; S.p.idx[wv*64 + lane] = bi;
      __syncthreads();
      if (wv == 0){
        float bb = S.p.red[lane]; int bbi = S.p.idx[lane];
        #pragma unroll
        for (int w2=1; w2<16; w2++){
          float vl = S.p.red[w2*64+lane]; int ii = S.p.idx[w2*64+lane];
          if (vl > bb || (vl == bb && ii < bbi)){ bb = vl; bbi = ii; }
        }
        gstoref(pPv + (t&1)*4096 + v*64 + lane, bb);
        gstorei(pPi + (t&1)*4096 + v*64 + lane, bbi);
        asm volatile("s_waitcnt vmcnt(0)" ::: "memory");
      }
      __syncthreads();
      if (tid == 0) gstorei(fP + v, t + 1);
      if (t == NPRED-1) continue;

      // ---- all-WG redundant reduce (v ascending) -> tokens in S.p.tok
      if (wv == 0){
        int g = 0;
        while (!__all(gload32(fP + lane) >= t+1) && ++g < (1<<24)) {}
        float bb = -INFINITY; int bbi = 0x7fffffff;
        for (int vs = 0; vs < 64; ++vs){
          float vl = gloadf(pPv + (t&1)*4096 + vs*64 + lane);
          int  ii  = gload32(pPi + (t&1)*4096 + vs*64 + lane);
          if (vl > bb || (vl == bb && ii < bbi)){ bb = vl; bbi = ii; }
        }
        S.p.tok[lane] = bbi;
      }
      __syncthreads();
      // gather emb rows directly -> htp[k*65+r]
      {
        #pragma unroll
        for (int i=0;i<16;i++){
          int idx = tid + i*1024;
          int k2 = idx >> 6, r2 = idx & 63;
          int tk = S.p.tok[r2];
          S.p.htp[k2*65 + r2] = emb[(size_t)tk*EMBD + k2];
        }
      }
      __syncthreads();
      // xproj of position t+1 (j-slice of 16)
      {
        int j = v*16 + jl;
        const float* Wj = Wih0 + (size_t)j*EMBD;
        float acc = b0v;
        #pragma unroll 16
        for (int k2=0;k2<256;k2++) acc += Wj[k2]*S.p.htp[k2*65 + rr];
        gstoref(xp + ((size_t)(t+1)*64 + rr)*G4 + v*16 + jl, acc);
        asm volatile("s_waitcnt vmcnt(0)" ::: "memory");
      }
      __syncthreads();
      if (tid == 0) gstorei(fX + v, t + 1);
    }
  }
}

// -------------------------------- launch ------------------------------------
extern "C" void kernel_launch(void* const* d_in, const int* in_sizes, int n_in,
                              void* d_out, int out_size, void* d_ws, size_t ws_size,
                              hipStream_t stream)
{
  const int*   input_seq  = (const int*)d_in[0];
  const int*   target_seq = (const int*)d_in[1];
  const float* enc_emb = (const float*)d_in[2];
  const float* dec_emb = (const float*)d_in[3];
  const float* enc_Wih = (const float*)d_in[4];
  const float* enc_Whh = (const float*)d_in[5];
  const float* enc_b   = (const float*)d_in[6];
  const float* dec_Wih = (const float*)d_in[7];
  const float* dec_Whh = (const float*)d_in[8];
  const float* dec_b   = (const float*)d_in[9];
  const float* W_out   = (const float*)d_in[10];
  const float* b_out   = (const float*)d_in[11];
  float* out = (float*)d_out;

  float* ws   = (float*)d_ws;
  float* xp_e = ws;                               // 64*64*1024
  float* xp_d = xp_e + (size_t)SLEN*64*G4;        // 32*64*1024
  float* h0P  = xp_d + (size_t)TLEN*64*G4;        // 256*64
  float* h1P  = h0P + HID*64;
  float* c0P  = h1P + HID*64;
  float* c1P  = c0P + HID*64;
  float* h0R  = c1P + HID*64;                     // 4*16384
  float* p1R  = h0R + 4*16384;                    // 4*65536
  float* h1R  = p1R + 4*65536;                    // 2*16384
  float* pPv  = h1R + 2*16384;                    // 2*4096
  int*   pPi  = (int*)(pPv + 2*4096);             // 2*4096
  int*   flags= (int*)(pPi + 2*4096);             // 512
  float* WT0  = (float*)(flags + 512);            // 3 * 256*1024
  float* WT1i = WT0  + HID*G4;
  float* WT1h = WT1i + HID*G4;

  k_zero<<<1, 512, 0, stream>>>(flags);

  dim3 trg(16, 4);
  // encoder
  k_tr<<<trg, 256, 0, stream>>>(enc_Whh,                   WT0);
  k_tr<<<trg, 256, 0, stream>>>(enc_Wih + (size_t)G4*EMBD, WT1i);
  k_tr<<<trg, 256, 0, stream>>>(enc_Whh + (size_t)G4*HID,  WT1h);
  k_xproj<<<dim3(32, SLEN), 256, 0, stream>>>(input_seq, SLEN, 0, enc_emb,
        enc_Wih, enc_b, xp_e);
  k_pipe<<<192, 1024, 0, stream>>>(xp_e, SLEN,
        WT0, WT1i, WT1h, enc_b + G4,
        h0P, h1P, c0P, c1P, h0R, p1R,
        flags, flags + 64, flags + 128, 0, 1);

  // decoder weights + BOS xproj (position 0)
  k_tr<<<trg, 256, 0, stream>>>(dec_Whh,                   WT0);
  k_tr<<<trg, 256, 0, stream>>>(dec_Wih + (size_t)G4*EMBD, WT1i);
  k_tr<<<trg, 256, 0, stream>>>(dec_Whh + (size_t)G4*HID,  WT1h);
  k_xproj<<<dim3(32, 1), 256, 0, stream>>>(target_seq, TLEN, 0, dec_emb,
        dec_Wih, dec_b, xp_d);

  // persistent decoder (2 rows per chain WG)
  k_megadec<<<256, 1024, 0, stream>>>(xp_d,
        WT0, WT1i, WT1h, dec_b + G4,
        dec_Wih, dec_b, dec_emb, W_out, b_out, out,
        h0P, h1P, c0P, c1P,
        h0R, p1R, h1R, pPv, pPi, flags);
}

// Round 16
// 9059.905 us; speedup vs baseline: 1.0375x; 1.0375x over previous
//
#include <hip/hip_runtime.h>
#include <math.h>

// ---------------------------------------------------------------------------
// Seq2SeqLSTM on MI355X -- Round 15: flag cache-line padding (single change).
//
// Evidence: megadec chain step ~17.3us INVARIANT across xp layout, NT policy,
// role placement, 2-row blocking; FETCH varied 2.3GB->1.1GB with no time
// effect. k_pipe (no P role) = 10.9us/step. Remaining delta: P/B2/A wide
// polls hammer flag words packed into the same cache lines as the ring's
// fA/fB1/fB2 -> same-line serialization at the coherence point inflates ring
// hops. R15 = R13 EXACTLY + (1) each flag on its own 64B line (stride 16
// ints), groups in separate 4KB pages; (2) P fH poll s_sleep(8).
// ---------------------------------------------------------------------------

#define B     64
#define SLEN  64
#define TLEN  32
#define HID   256
#define EMBD  256
#define G4    1024
#define VOC   32000
#define NPRED 31
#define FBASE 64
#define FS    16          // flag stride in ints (64B line per flag)

typedef unsigned long long u64;

__device__ __forceinline__ float sigf(float x){ return 1.0f/(1.0f+__expf(-x)); }

__device__ __forceinline__ void gstoref(float* p, float v){
  __hip_atomic_store(p, v, __ATOMIC_RELAXED, __HIP_MEMORY_SCOPE_AGENT);
}
__device__ __forceinline__ void gstorei(int* p, int v){
  __hip_atomic_store(p, v, __ATOMIC_RELAXED, __HIP_MEMORY_SCOPE_AGENT);
}
__device__ __forceinline__ float gloadf(const float* p){
  return __hip_atomic_load(p, __ATOMIC_RELAXED, __HIP_MEMORY_SCOPE_AGENT);
}
__device__ __forceinline__ int gload32(const int* p){
  return __hip_atomic_load(p, __ATOMIC_RELAXED, __HIP_MEMORY_SCOPE_AGENT);
}

// --------------------------------- zero ------------------------------------
__global__ void k_zero(int* __restrict__ p){
  p[blockIdx.x*1024 + threadIdx.x] = 0;   // grid 6 x 1024
}

// ------------------------------- transpose ----------------------------------
__global__ __launch_bounds__(256) void k_tr(const float* __restrict__ src,
                                            float* __restrict__ dst){
  __shared__ float t[64][65];
  const int r0 = blockIdx.x*64, c0 = blockIdx.y*64;
  const int lr = threadIdx.x>>6, lc = threadIdx.x&63;
  #pragma unroll
  for (int i=0;i<16;i++){
    int r = lr + i*4;
    t[r][lc] = src[(size_t)(r0+r)*256 + c0+lc];
  }
  __syncthreads();
  #pragma unroll
  for (int i=0;i<16;i++){
    int c = lr + i*4;
    dst[(size_t)(c0+c)*1024 + r0+lc] = t[lc][c];
  }
}

// --------------------------------- xproj -----------------------------------
// layout: out[(pos*64 + r)*G4 + j]
__global__ __launch_bounds__(256) void k_xproj(
    const int* __restrict__ tok, int tok_stride, int pos0,
    const float* __restrict__ emb, const float* __restrict__ W,
    const float* __restrict__ b0, float* __restrict__ out)
{
  __shared__ float xT[128][64];
  const int tid  = threadIdx.x;
  const int lane = tid & 63;
  const int wv   = __builtin_amdgcn_readfirstlane(tid >> 6);
  const int pos  = pos0 + blockIdx.y;
  const int jbase= blockIdx.x*32 + wv*8;

  const int rS = tid >> 2, klane = tid & 3;
  const int tokrow = tok[rS*tok_stride + pos];
  const float* xsrc = emb + (size_t)tokrow*EMBD;

  float acc[8];
  #pragma unroll
  for (int jj=0;jj<8;jj++) acc[jj]=0.f;

  for (int c=0;c<2;c++){
    __syncthreads();
    #pragma unroll
    for (int i=0;i<32;i++){
      int k = klane + 4*i;
      xT[k][rS] = xsrc[c*128 + k];
    }
    __syncthreads();
    for (int kc=0;kc<8;kc++){
      float x[16];
      #pragma unroll
      for (int i=0;i<16;i++) x[i] = xT[kc*16+i][lane];
      #pragma unroll
      for (int jj=0;jj<8;jj++){
        const float* Wp = W + (size_t)(jbase+jj)*EMBD + c*128 + kc*16;
        float s = 0.f;
        #pragma unroll
        for (int i=0;i<16;i++) s += Wp[i]*x[i];
        acc[jj] += s;
      }
    }
  }
  #pragma unroll
  for (int jj=0;jj<8;jj++){
    int j = jbase+jj;
    out[((size_t)pos*64 + lane)*G4 + j] = acc[jj] + b0[j];
  }
}

// ------------------------------- dotpart ------------------------------------
__device__ __forceinline__ float4 dotpart(const float4* __restrict__ Wq,
                                          const float* __restrict__ hs,
                                          int kq, int jg){
  float ax=0.f, ay=0.f, az=0.f, aw=0.f;
  const float4* __restrict__ hq = (const float4*)(hs + (kq<<6));
  const float4* __restrict__ w  = Wq + (size_t)(kq<<6)*256 + jg;
  #pragma unroll 4
  for (int kk=0; kk<16; ++kk){
    float4 h4 = hq[kk];
    float4 w0 = w[0];
    float4 w1 = w[256];
    float4 w2 = w[512];
    float4 w3 = w[768];
    ax += w0.x*h4.x; ay += w0.y*h4.x; az += w0.z*h4.x; aw += w0.w*h4.x;
    ax += w1.x*h4.y; ay += w1.y*h4.y; az += w1.z*h4.y; aw += w1.w*h4.y;
    ax += w2.x*h4.z; ay += w2.y*h4.z; az += w2.z*h4.z; aw += w2.w*h4.z;
    ax += w3.x*h4.w; ay += w3.y*h4.w; az += w3.z*h4.w; aw += w3.w*h4.w;
    w += 1024;
  }
  return make_float4(ax,ay,az,aw);
}

// --------------------------- encoder pipe (R8) -------------------------------
__global__ __launch_bounds__(1024) void k_pipe(
    const float* __restrict__ xp, int nsteps,
    const float* __restrict__ WT0, const float* __restrict__ WT1i,
    const float* __restrict__ WT1h, const float* __restrict__ b1,
    float* __restrict__ h0P, float* __restrict__ h1P,
    float* __restrict__ c0P, float* __restrict__ c1P,
    float* __restrict__ h0R, float* __restrict__ p1R,
    int* __restrict__ fA, int* __restrict__ fB1, int* __restrict__ fB2,
    int fbase, int initzero)
{
  __shared__ __align__(16) float part[4][4096];
  __shared__ float xps[1024];
  __shared__ __align__(16) float hloc[256];
  __shared__ float padL[4096];
  const int tid  = threadIdx.x;
  const int kq   = tid >> 8, jg = tid & 255;
  const int role = blockIdx.x >> 6;
  const int r    = blockIdx.x & 63;
  if (nsteps < 0){ padL[tid] = xp[tid]; h0R[tid] = padL[tid ^ 1]; }

  if (role == 0){
    float c0 = 0.f;
    if (tid < HID){
      if (initzero){ c0 = 0.f; hloc[tid] = 0.f; }
      else { c0 = c0P[tid*64 + r]; hloc[tid] = h0P[tid*64 + r]; }
    }
    __syncthreads();
    const float4* W4 = (const float4*)WT0;
    for (int q = 0; q < nsteps; ++q){
      float xv = xp[((size_t)q*64 + r)*G4 + tid];
      if (tid == 0 && q >= 4){
        int tgt = fbase + q - 3, g = 0;
        while (gload32(fB1 + r*FS) < tgt && ++g < (1<<24)) {}
      }
      float4 a = dotpart(W4, hloc, kq, jg);
      xps[tid] = xv;
      *(float4*)&part[kq][jg<<2] = a;
      __syncthreads();
      if (tid < HID){
        float g0 = part[0][tid]+part[1][tid]+part[2][tid]+part[3][tid] + xps[tid];
        float g1 = part[0][HID+tid]+part[1][HID+tid]+part[2][HID+tid]+part[3][HID+tid] + xps[HID+tid];
        float g2 = part[0][2*HID+tid]+part[1][2*HID+tid]+part[2][2*HID+tid]+part[3][2*HID+tid] + xps[2*HID+tid];
        float g3 = part[0][3*HID+tid]+part[1][3*HID+tid]+part[2][3*HID+tid]+part[3][3*HID+tid] + xps[3*HID+tid];
        c0 = sigf(g1)*c0 + sigf(g0)*tanhf(g2);
        float h = sigf(g3)*tanhf(c0);
        hloc[tid] = h;
        gstoref(h0R + (q&3)*16384 + r*256 + tid, h);
        asm volatile("s_waitcnt vmcnt(0)" ::: "memory");
      }
      __syncthreads();
      if (tid == 0) gstorei(fA + r*FS, fbase + q + 1);
    }
    if (tid < HID){ c0P[tid*64 + r] = c0; h0P[tid*64 + r] = hloc[tid]; }
  }
  else if (role == 1){
    const float4* W4 = (const float4*)WT1i;
    for (int q = 0; q < nsteps; ++q){
      if (tid == 0){
        int tgt = fbase + q + 1, g = 0;
        while (gload32(fA + r*FS) < tgt && ++g < (1<<24)) {}
        if (q >= 4){
          int t2 = fbase + q - 3; g = 0;
          while (gload32(fB2 + r*FS) < t2 && ++g < (1<<24)) {}
        }
      }
      __syncthreads();
      if (tid < HID) hloc[tid] = gloadf(h0R + (q&3)*16384 + r*256 + tid);
      __syncthreads();
      float4 a = dotpart(W4, hloc, kq, jg);
      *(float4*)&part[kq][jg<<2] = a;
      __syncthreads();
      float p = part[0][tid]+part[1][tid]+part[2][tid]+part[3][tid];
      gstoref(p1R + (q&3)*65536 + r*1024 + tid, p);
      asm volatile("s_waitcnt vmcnt(0)" ::: "memory");
      __syncthreads();
      if (tid == 0) gstorei(fB1 + r*FS, fbase + q + 1);
    }
  }
  else {
    float c1 = 0.f, bb0=0.f, bb1=0.f, bb2=0.f, bb3=0.f;
    if (tid < HID){
      bb0 = b1[tid]; bb1 = b1[HID+tid]; bb2 = b1[2*HID+tid]; bb3 = b1[3*HID+tid];
      if (initzero){ c1 = 0.f; hloc[tid] = 0.f; }
      else { c1 = c1P[tid*64 + r]; hloc[tid] = h1P[tid*64 + r]; }
    }
    __syncthreads();
    const float4* W4 = (const float4*)WT1h;
    for (int q = 0; q < nsteps; ++q){
      if (tid == 0){
        int tgt = fbase + q + 1, g = 0;
        while (gload32(fB1 + r*FS) < tgt && ++g < (1<<24)) {}
      }
      __syncthreads();
      xps[tid] = gloadf(p1R + (q&3)*65536 + r*1024 + tid);
      asm volatile("s_waitcnt vmcnt(0)" ::: "memory");
      __syncthreads();
      if (tid == 0) gstorei(fB2 + r*FS, fbase + q + 1);
      float4 a = dotpart(W4, hloc, kq, jg);
      *(float4*)&part[kq][jg<<2] = a;
      __syncthreads();
      if (tid < HID){
        float g0 = part[0][tid]+part[1][tid]+part[2][tid]+part[3][tid] + xps[tid] + bb0;
        float g1 = part[0][HID+tid]+part[1][HID+tid]+part[2][HID+tid]+part[3][HID+tid] + xps[HID+tid] + bb1;
        float g2 = part[0][2*HID+tid]+part[1][2*HID+tid]+part[2][2*HID+tid]+part[3][2*HID+tid] + xps[2*HID+tid] + bb2;
        float g3 = part[0][3*HID+tid]+part[1][3*HID+tid]+part[2][3*HID+tid]+part[3][3*HID+tid] + xps[3*HID+tid] + bb3;
        c1 = sigf(g1)*c1 + sigf(g0)*tanhf(g2);
        float h = sigf(g3)*tanhf(c1);
        hloc[tid] = h;
        if (q == nsteps-1) h1P[tid*64 + r] = h;
      }
      __syncthreads();
    }
    if (tid < HID) c1P[tid*64 + r] = c1;
  }
}

// ------------------------- persistent decoder --------------------------------
// flags (padded, FS=16 ints per flag; 4KB page per group):
//   fA = flags+0, fB1 = flags+1024, fB2 = flags+2048,
//   fH = flags+3072, fP = flags+4096, fX = flags+5120.
// WG map: xcd=bid&7, role=xcd>>1, r=((xcd&1)<<5)|(bid>>3).
__global__ __launch_bounds__(1024) void k_megadec(
    float* xp,
    const float* __restrict__ WT0, const float* __restrict__ WT1i,
    const float* __restrict__ WT1h, const float* __restrict__ b1,
    const float* __restrict__ Wih0, const float* __restrict__ b0,
    const float* __restrict__ emb,
    const float* __restrict__ Wout, const float* __restrict__ bout,
    float* __restrict__ dout,
    const float* __restrict__ h0P, const float* __restrict__ h1P,
    const float* __restrict__ c0P, const float* __restrict__ c1P,
    float* __restrict__ h0R, float* __restrict__ p1R, float* __restrict__ h1R,
    float* __restrict__ pPv, int* __restrict__ pPi,
    int* __restrict__ flags)
{
  __shared__ __align__(16) float part[4][4096];   // 64 KB
  __shared__ float xps[1024];                     //  4 KB
  __shared__ __align__(16) float hloc[256];       //  1 KB
  __shared__ int   iscr[1024];                    //  4 KB
  __shared__ float htp[256*65];                   // 65 KB

  int* fA = flags;          int* fB1 = flags + 1024;  int* fB2 = flags + 2048;
  int* fH = flags + 3072;   int* fP  = flags + 4096;  int* fX  = flags + 5120;

  const int tid  = threadIdx.x;
  const int lane = tid & 63;
  const int wv   = __builtin_amdgcn_readfirstlane(tid >> 6);
  const int kq   = tid >> 8, jg = tid & 255;
  const int xcd  = blockIdx.x & 7;
  const int role = xcd >> 1;
  const int r    = ((xcd & 1) << 5) | (blockIdx.x >> 3);   // 0..63

  // =========================== role A: layer 0 =============================
  if (role == 0){
    float c0 = 0.f;
    if (tid < HID){ c0 = c0P[tid*64 + r]; hloc[tid] = h0P[tid*64 + r]; }
    __syncthreads();
    const float4* W4 = (const float4*)WT0;
    int cum = 0;
    for (int t = 0; t < NPRED; ++t)
    for (int p = 0; p <= t; ++p, ++cum){
      if (wv == 0){
        if (lane == 0 && cum >= 4){
          int tgt = FBASE + cum - 3, g = 0;
          while (gload32(fB1 + r*FS) < tgt && ++g < (1<<24)) {}
        }
        if (p == t && t >= 1){
          int g = 0;
          while (!__all(gload32(fX + lane*FS) >= t) && ++g < (1<<24)) {}
        }
      }
      __syncthreads();
      const float* xa = xp + ((size_t)p*64 + r)*G4 + tid;
      float xv = (p == t) ? gloadf(xa) : *xa;
      float4 a = dotpart(W4, hloc, kq, jg);
      xps[tid] = xv;
      *(float4*)&part[kq][jg<<2] = a;
      __syncthreads();
      if (tid < HID){
        float g0 = part[0][tid]+part[1][tid]+part[2][tid]+part[3][tid] + xps[tid];
        float g1 = part[0][HID+tid]+part[1][HID+tid]+part[2][HID+tid]+part[3][HID+tid] + xps[HID+tid];
        float g2 = part[0][2*HID+tid]+part[1][2*HID+tid]+part[2][2*HID+tid]+part[3][2*HID+tid] + xps[2*HID+tid];
        float g3 = part[0][3*HID+tid]+part[1][3*HID+tid]+part[2][3*HID+tid]+part[3][3*HID+tid] + xps[3*HID+tid];
        c0 = sigf(g1)*c0 + sigf(g0)*tanhf(g2);
        float h = sigf(g3)*tanhf(c0);
        hloc[tid] = h;
        gstoref(h0R + (cum&3)*16384 + r*256 + tid, h);
        asm volatile("s_waitcnt vmcnt(0)" ::: "memory");
      }
      __syncthreads();
      if (tid == 0) gstorei(fA + r*FS, FBASE + cum + 1);
    }
  }
  // =========================== role B1: Wih1.h0 ============================
  else if (role == 1){
    const float4* W4 = (const float4*)WT1i;
    int cum = 0;
    for (int t = 0; t < NPRED; ++t)
    for (int p = 0; p <= t; ++p, ++cum){
      if (tid == 0){
        int tgt = FBASE + cum + 1, g = 0;
        while (gload32(fA + r*FS) < tgt && ++g < (1<<24)) {}
        if (cum >= 4){
          int t2 = FBASE + cum - 3; g = 0;
          while (gload32(fB2 + r*FS) < t2 && ++g < (1<<24)) {}
        }
      }
      __syncthreads();
      if (tid < HID) hloc[tid] = gloadf(h0R + (cum&3)*16384 + r*256 + tid);
      __syncthreads();
      float4 a = dotpart(W4, hloc, kq, jg);
      *(float4*)&part[kq][jg<<2] = a;
      __syncthreads();
      float pp = part[0][tid]+part[1][tid]+part[2][tid]+part[3][tid];
      gstoref(p1R + (cum&3)*65536 + r*1024 + tid, pp);
      asm volatile("s_waitcnt vmcnt(0)" ::: "memory");
      __syncthreads();
      if (tid == 0) gstorei(fB1 + r*FS, FBASE + cum + 1);
    }
  }
  // ================== role B2: Whh1.h1 + combine + act =====================
  else if (role == 2){
    float c1 = 0.f, bb0=0.f, bb1=0.f, bb2=0.f, bb3=0.f;
    if (tid < HID){
      bb0 = b1[tid]; bb1 = b1[HID+tid]; bb2 = b1[2*HID+tid]; bb3 = b1[3*HID+tid];
      c1 = c1P[tid*64 + r]; hloc[tid] = h1P[tid*64 + r];
    }
    __syncthreads();
    const float4* W4 = (const float4*)WT1h;
    int cum = 0;
    for (int t = 0; t < NPRED; ++t)
    for (int p = 0; p <= t; ++p, ++cum){
      if (tid == 0){
        int tgt = FBASE + cum + 1, g = 0;
        while (gload32(fB1 + r*FS) < tgt && ++g < (1<<24)) {}
      }
      __syncthreads();
      xps[tid] = gloadf(p1R + (cum&3)*65536 + r*1024 + tid);
      asm volatile("s_waitcnt vmcnt(0)" ::: "memory");
      __syncthreads();
      if (tid == 0) gstorei(fB2 + r*FS, FBASE + cum + 1);
      float4 a = dotpart(W4, hloc, kq, jg);
      *(float4*)&part[kq][jg<<2] = a;
      __syncthreads();
      if (tid < HID){
        float g0 = part[0][tid]+part[1][tid]+part[2][tid]+part[3][tid] + xps[tid] + bb0;
        float g1 = part[0][HID+tid]+part[1][HID+tid]+part[2][HID+tid]+part[3][HID+tid] + xps[HID+tid] + bb1;
        float g2 = part[0][2*HID+tid]+part[1][2*HID+tid]+part[2][2*HID+tid]+part[3][2*HID+tid] + xps[2*HID+tid] + bb2;
        float g3 = part[0][3*HID+tid]+part[1][3*HID+tid]+part[2][3*HID+tid]+part[3][3*HID+tid] + xps[3*HID+tid] + bb3;
        c1 = sigf(g1)*c1 + sigf(g0)*tanhf(g2);
        float h = sigf(g3)*tanhf(c1);
        hloc[tid] = h;
      }
      __syncthreads();
      if (p == t){
        if (tid == 0 && t >= 2){
          int g = 0;
          while (gload32(fP) < t - 1 && ++g < (1<<24)) {}   // fP[0] as proxy? no:
        }
        // gate h1R slot reuse on ALL pred(t-2) done (wave-wide check)
        if (wv == 1 && t >= 2){
          int g = 0;
          while (!__all(gload32(fP + lane*FS) >= t-1) && ++g < (1<<24)) {}
        }
        __syncthreads();
        if (tid < HID){
          gstoref(h1R + (t&1)*16384 + r*256 + tid, hloc[tid]);
          asm volatile("s_waitcnt vmcnt(0)" ::: "memory");
        }
        __syncthreads();
        if (tid == 0) gstorei(fH + r*FS, t + 1);
      }
    }
  }
  // ================== role P: pred + argmax + xproj ========================
  else {
    const int v  = r;
    const int v0 = v * 500;
    const int rr = tid >> 4;
    const int jl = tid & 15;
    const float b0v = b0[v*16 + jl];

    for (int t = 0; t < NPRED; ++t){
      if (wv == 0){
        int g = 0;
        while (!__all(gload32(fH + lane*FS) >= t+1) && ++g < (1<<24))
          __builtin_amdgcn_s_sleep(8);
      }
      __syncthreads();
      {
        const float* src = h1R + (size_t)(t&1)*16384;
        #pragma unroll
        for (int i=0;i<16;i++){
          int idx = tid + i*1024;
          float vl = gloadf(src + idx);
          htp[(idx & 255)*65 + (idx >> 8)] = vl;
        }
      }
      __syncthreads();
      float best = -INFINITY; int bi = 0x7fffffff;
      for (int ib = 0; ib < 4; ++ib){
        float acc[8];
        #pragma unroll
        for (int jj=0;jj<8;jj++){
          int i = ib*8+jj;
          acc[jj] = (wv + 16*i < 500) ? bout[v0 + wv + 16*i] : 0.f;
        }
        for (int kc = 0; kc < 16; ++kc){
          float x[16];
          #pragma unroll
          for (int u=0;u<16;u++) x[u] = htp[(kc*16+u)*65 + lane];
          #pragma unroll
          for (int jj=0;jj<8;jj++){
            int i = ib*8+jj;
            if (wv + 16*i < 500){
              const float* Wp = Wout + (size_t)(v0 + wv + 16*i)*HID + kc*16;
              #pragma unroll
              for (int u=0;u<16;u++) acc[jj] += Wp[u]*x[u];
            }
          }
        }
        #pragma unroll
        for (int jj=0;jj<8;jj++){
          int i = ib*8+jj;
          if (wv + 16*i < 500){
            int vv = v0 + wv + 16*i;
            dout[((size_t)lane*NPRED + t)*VOC + vv] = acc[jj];
            if (acc[jj] > best){ best = acc[jj]; bi = vv; }
          }
        }
      }
      xps[wv*64 + lane] = best; iscr[wv*64 + lane] = bi;
      __syncthreads();
      if (wv == 0){
        float bb = xps[lane]; int bbi = iscr[lane];
        #pragma unroll
        for (int w=1; w<16; w++){
          float vl = xps[w*64+lane]; int ii = iscr[w*64+lane];
          if (vl > bb || (vl == bb && ii < bbi)){ bb = vl; bbi = ii; }
        }
        gstoref(pPv + (t&1)*4096 + v*64 + lane, bb);
        gstorei(pPi + (t&1)*4096 + v*64 + lane, bbi);
        asm volatile("s_waitcnt vmcnt(0)" ::: "memory");
      }
      __syncthreads();
      if (tid == 0) gstorei(fP + v*FS, t + 1);
      if (t == NPRED-1) continue;

      // all-WG redundant reduce (v ascending) -> tokens
      if (wv == 0){
        int g = 0;
        while (!__all(gload32(fP + lane*FS) >= t+1) && ++g < (1<<24)) {}
        float bb = -INFINITY; int bbi = 0x7fffffff;
        for (int vs = 0; vs < 64; ++vs){
          float vl = gloadf(pPv + (t&1)*4096 + vs*64 + lane);
          int  ii  = gload32(pPi + (t&1)*4096 + vs*64 + lane);
          if (vl > bb || (vl == bb && ii < bbi)){ bb = vl; bbi = ii; }
        }
        iscr[lane] = bbi;
      }
      __syncthreads();
      {
        #pragma unroll
        for (int i=0;i<16;i++){
          int idx = tid + i*1024;
          int k2 = idx >> 6, r2 = idx & 63;
          int tk = iscr[r2];
          htp[k2*65 + r2] = emb[(size_t)tk*EMBD + k2];
        }
      }
      __syncthreads();
      {
        int j = v*16 + jl;
        const float* Wj = Wih0 + (size_t)j*EMBD;
        float acc = b0v;
        #pragma unroll 16
        for (int k2=0;k2<256;k2++) acc += Wj[k2]*htp[k2*65 + rr];
        gstoref(xp + ((size_t)(t+1)*64 + rr)*G4 + v*16 + jl, acc);
        asm volatile("s_waitcnt vmcnt(0)" ::: "memory");
      }
      __syncthreads();
      if (tid == 0) gstorei(fX + v*FS, t + 1);
    }
  }
}

// -------------------------------- launch ------------------------------------
extern "C" void kernel_launch(void* const* d_in, const int* in_sizes, int n_in,
                              void* d_out, int out_size, void* d_ws, size_t ws_size,
                              hipStream_t stream)
{
  const int*   input_seq  = (const int*)d_in[0];
  const int*   target_seq = (const int*)d_in[1];
  const float* enc_emb = (const float*)d_in[2];
  const float* dec_emb = (const float*)d_in[3];
  const float* enc_Wih = (const float*)d_in[4];
  const float* enc_Whh = (const float*)d_in[5];
  const float* enc_b   = (const float*)d_in[6];
  const float* dec_Wih = (const float*)d_in[7];
  const float* dec_Whh = (const float*)d_in[8];
  const float* dec_b   = (const float*)d_in[9];
  const float* W_out   = (const float*)d_in[10];
  const float* b_out   = (const float*)d_in[11];
  float* out = (float*)d_out;

  float* ws   = (float*)d_ws;
  float* xp_e = ws;                               // 64*64*1024
  float* xp_d = xp_e + (size_t)SLEN*64*G4;        // 32*64*1024
  float* h0P  = xp_d + (size_t)TLEN*64*G4;        // 256*64
  float* h1P  = h0P + HID*64;
  float* c0P  = h1P + HID*64;
  float* c1P  = c0P + HID*64;
  float* h0R  = c1P + HID*64;                     // 4*16384
  float* p1R  = h0R + 4*16384;                    // 4*65536
  float* h1R  = p1R + 4*65536;                    // 2*16384
  float* pPv  = h1R + 2*16384;                    // 2*4096
  int*   pPi  = (int*)(pPv + 2*4096);             // 2*4096
  int*   flags= (int*)(pPi + 2*4096);             // 6*1024 (padded groups)
  float* WT0  = (float*)(flags + 6144);           // 3 * 256*1024
  float* WT1i = WT0  + HID*G4;
  float* WT1h = WT1i + HID*G4;

  k_zero<<<6, 1024, 0, stream>>>(flags);

  dim3 trg(16, 4);
  // encoder
  k_tr<<<trg, 256, 0, stream>>>(enc_Whh,                   WT0);
  k_tr<<<trg, 256, 0, stream>>>(enc_Wih + (size_t)G4*EMBD, WT1i);
  k_tr<<<trg, 256, 0, stream>>>(enc_Whh + (size_t)G4*HID,  WT1h);
  k_xproj<<<dim3(32, SLEN), 256, 0, stream>>>(input_seq, SLEN, 0, enc_emb,
        enc_Wih, enc_b, xp_e);
  k_pipe<<<192, 1024, 0, stream>>>(xp_e, SLEN,
        WT0, WT1i, WT1h, enc_b + G4,
        h0P, h1P, c0P, c1P, h0R, p1R,
        flags, flags + 1024, flags + 2048, 0, 1);

  // decoder weights + BOS xproj (position 0)
  k_tr<<<trg, 256, 0, stream>>>(dec_Whh,                   WT0);
  k_tr<<<trg, 256, 0, stream>>>(dec_Wih + (size_t)G4*EMBD, WT1i);
  k_tr<<<trg, 256, 0, stream>>>(dec_Whh + (size_t)G4*HID,  WT1h);
  k_xproj<<<dim3(32, 1), 256, 0, stream>>>(target_seq, TLEN, 0, dec_emb,
        dec_Wih, dec_b, xp_d);

  // persistent decoder
  k_megadec<<<256, 1024, 0, stream>>>(xp_d,
        WT0, WT1i, WT1h, dec_b + G4,
        dec_Wih, dec_b, dec_emb, W_out, b_out, out,
        h0P, h1P, c0P, c1P,
        h0R, p1R, h1R, pPv, pPi, flags);
}